// Round 7
// baseline (401.556 us; speedup 1.0000x reference)
//
#include <hip/hip_runtime.h>

// GaranAttentionV2: b=32, l=64, d_q=1024, c=d_o=512, n_head=8, dk=64, h=w=32, hw=1024
// R11: hybrid coherence. R10 post-mortem: LLC relaxed atomics cost ~1
// transaction/lane (no coalescing, no cache) -> ~100us of memory-pipe
// serialization across k2/k7/phase-B/epilogue. Fix: intermediates are WRITTEN
// with agent-relaxed atomic stores (write-through to LLC; L2 never dirty) but
// READ with plain cached coalesced loads; each grid barrier ends with an
// ACQUIRE fence (buffer_inv only -- no wbl2) executed by all threads after the
// release flag is observed. Distributed-arrive barrier unchanged (proven R9).
// bq hotspot (block 0 serial loop) distributed to sc==0 blocks via LDS qs.
// Everything else byte-identical to R10's passing kernel. Bounded spins.
// Fallback (attr failure): proven 7-kernel path (347us).

#define BB 32
#define LL 64
#define DQn 1024
#define CCn 512
#define NH 8
#define DKn 64
#define HWn 1024
#define NBLK 512
#define SLOTSTRIDE 16   // u32s; 64B between slots -> no line sharing

typedef unsigned short u16;
typedef unsigned int u32;
typedef unsigned long long u64;

__device__ __forceinline__ float bfr(u16 u) {
    return __uint_as_float(((u32)u) << 16);
}
__device__ __forceinline__ u16 f2bf(float f) {
    u32 x = __float_as_uint(f);
    u32 r = (x + 0x7FFFu + ((x >> 16) & 1u)) >> 16;
    return (u16)r;
}

// Write-through (LLC-coherent) stores for cross-block intermediates.
__device__ __forceinline__ void cst(float* p, float v) {
    __hip_atomic_store(p, v, __ATOMIC_RELAXED, __HIP_MEMORY_SCOPE_AGENT);
}
__device__ __forceinline__ u32 cldu(const u32* p) {
    return __hip_atomic_load(const_cast<u32*>(p), __ATOMIC_RELAXED,
                             __HIP_MEMORY_SCOPE_AGENT);
}
__device__ __forceinline__ void cstu(u32* p, u32 v) {
    __hip_atomic_store(p, v, __ATOMIC_RELAXED, __HIP_MEMORY_SCOPE_AGENT);
}

// ---------------------------------------------------------------------------
#define POOLB 78080

struct MArgs {
    const float *q, *v, *wqs, *bqs, *wkc, *bkc, *wkd, *bkd, *wvs, *bvs, *wm, *wmb,
                *gam, *bet, *mea, *var;
    float *qsp, *qs, *wq, *bq, *dsig, *sums, *attn, *A2g, *pvp;
    u32* bar;   // [0..7] unused, [8..12]=flags, [16..16+NBLK*SLOTSTRIDE)=slots
    float *out0, *out1, *out2;
};

// Distributed-arrive grid barrier (proven R9) + acquire fence on exit.
// Stores are write-through (LLC) and drained by the pre-barrier syncthreads;
// the exit fence (buffer_inv, invalidate-only) makes subsequent PLAIN cached
// loads see LLC data. Fence runs in every thread strictly after the release
// flag was observed (post-syncthreads). Bounded: never hangs.
__device__ __forceinline__ void gbar(u32* bar, int i) {
    u32* slots = bar + 16;
    u32 epoch = (u32)(i + 1);
    __syncthreads();
    int t = threadIdx.x;
    if (blockIdx.x == (u32)(NBLK - 1)) {
        if (t < 64) {
            if (t == 0) cstu(&slots[(NBLK - 1) * SLOTSTRIDE], epoch);
            int base = t * (NBLK / 64);
            int it = 0;
            for (;;) {
                bool ok = true;
#pragma unroll
                for (int k = 0; k < NBLK / 64; ++k)
                    ok = ok && (cldu(&slots[(base + k) * SLOTSTRIDE]) == epoch);
                if (__all(ok)) break;
                __builtin_amdgcn_s_sleep(1);
                if (++it > (1 << 15)) break;   // failsafe
            }
            if (t == 0) cstu(&bar[8 + i], 1u);
        }
    } else if (t == 0) {
        cstu(&slots[blockIdx.x * SLOTSTRIDE], epoch);
        int it = 0;
        while (cldu(&bar[8 + i]) == 0u) {
            __builtin_amdgcn_s_sleep(2);
            if (++it > (1 << 18)) break;       // failsafe
        }
    }
    __syncthreads();
    __builtin_amdgcn_fence(__ATOMIC_ACQUIRE, "agent");   // buffer_inv: fresh reads
}

__global__ void kinit(u32* bar) {
    int t = threadIdx.x + blockIdx.x * blockDim.x;
    int total = 16 + NBLK * SLOTSTRIDE;
    for (int i = t; i < total; i += blockDim.x * gridDim.x)
        cstu(&bar[i], 0u);
}

#define PVACC(accv, eA, eB, vf) \
    accv[0] += eA.x * (vf); accv[1] += eA.y * (vf); accv[2] += eA.z * (vf); accv[3] += eA.w * (vf); \
    accv[4] += eB.x * (vf); accv[5] += eB.y * (vf); accv[6] += eB.z * (vf); accv[7] += eB.w * (vf);

// LDS pool: vtd[0,65536) u32[512*32] | red[65536,69888) f32[64*17]
//           etb[69888,71936) f32[64*8] | ext[71936,78080) f32[1536]
// Phase-B wqL chunk buffer overlays etb+ext: [69888,78080) = 2048 f32.
__global__ void __launch_bounds__(256, 2) mega(MArgs A) {
    extern __shared__ char pool[];
    u32*   vtd = (u32*)pool;
    float* red = (float*)(pool + 65536);
    float* etb = (float*)(pool + 69888);
    float* ext = (float*)(pool + 71936);
    float* scr2  = red;
    float* pvl   = etb;
    float* scr7  = red;
    float* al7   = red + 320;
    float* sinvp = red + 384;
    float* dsl   = red;
    float* A2l   = red + 512;
    u16*   k8s   = (u16*)etb;
    float* al    = ext;
    float* bnA   = ext + 512;
    float* bnB   = ext + 1024;

    int t = threadIdx.x;
    int bid = blockIdx.x;
    int sc = bid & 15, b = bid >> 4;
    int s0 = sc * 64;

    // ---- k1: qsp[b1,dq] = sum_l q[b1,l,dq]  (blocks 0..127) ----
    if (bid < 128) {
        int b1 = bid >> 2;
        int dq = (bid & 3) * 256 + t;
        const float* qp = A.q + (size_t)b1 * LL * DQn + dq;
        float acc = 0.f;
#pragma unroll 8
        for (int l = 0; l < LL; ++l) acc += qp[l * DQn];
        cst(&A.qsp[b1 * DQn + dq], acc);
    }

    // ---- phase A: stage v chunk (512 c x 64 s) into LDS bf16, swizzled ----
    {
        int sp = t & 31, c2 = t >> 5;
        const float* vb = A.v + (((size_t)(b * CCn + c2 * 64)) << 10) + s0 + sp * 2;
#pragma unroll 8
        for (int cr = 0; cr < 64; ++cr) {
            int r = c2 * 64 + cr;
            float2 xv = *reinterpret_cast<const float2*>(vb + ((size_t)cr << 10));
            u32 w = (u32)f2bf(xv.x) | ((u32)f2bf(xv.y) << 16);
            vtd[r * 32 + (sp ^ (r & 31))] = w;
        }
    }
    gbar(A.bar, 0);   // S1: qsp ready

    // ---- k2: qs[b,dof] (dof = bid); qsp via plain cached float4 ----
    {
        int dof = bid;
        int b2 = t & 31, ch = t >> 5;
        const float* wrow = A.wqs + (size_t)dof * DQn + ch * 128;
        const float* qrow = A.qsp + (size_t)b2 * DQn + ch * 128;
        float acc = 0.f;
#pragma unroll 8
        for (int i = 0; i < 128; i += 4) {
            float4 wv = *reinterpret_cast<const float4*>(wrow + i);
            float4 qv = *reinterpret_cast<const float4*>(qrow + i);
            acc += wv.x * qv.x + wv.y * qv.y + wv.z * qv.z + wv.w * qv.w;
        }
        scr2[t] = acc;
        __syncthreads();
        if (t < 32) {
            float a = 0.f;
#pragma unroll
            for (int c2 = 0; c2 < 8; ++c2) a += scr2[c2 * 32 + t];
            cst(&A.qs[t * CCn + dof], a + 64.f * A.bqs[dof]);
        }
    }
    gbar(A.bar, 1);   // S2: qs ready

    // ---- stage qs[b][*] into etb (plain cached) ----
    {
        float2 p = *reinterpret_cast<const float2*>(&A.qs[b * CCn + t * 2]);
        etb[t * 2] = p.x; etb[t * 2 + 1] = p.y;
    }
    __syncthreads();

    // ---- bq: distributed to sc==0 blocks (own b, from LDS qs) ----
    if (sc == 0 && t < 16) {
        int wsel = t >> 3, n = t & 7;
        const float* bw = wsel ? A.bkd : A.bkc;
        float a2 = 0.f;
#pragma unroll 8
        for (int d = 0; d < DKn; ++d)
            a2 += etb[n * DKn + d] * bw[n * DKn + d];
        cst(&A.bq[wsel * 256 + b * 8 + n], a2);
    }

    // ---- k3: wq coefficients (cc = sc, both wsel); qs from LDS ----
    {
        int cl = t & 31, n3 = t >> 5;
        int c = sc * 32 + cl;
#pragma unroll
        for (int wsel = 0; wsel < 2; ++wsel) {
            const float* w = wsel ? A.wkd : A.wkc;
            const float* qrow = etb + n3 * DKn;
            const float* wrow = w + (size_t)(n3 * DKn) * CCn + c;
            float acc = 0.f;
#pragma unroll 8
            for (int d = 0; d < DKn; ++d) acc += qrow[d] * wrow[(size_t)d * CCn];
            cst(&A.wq[((size_t)b * CCn + c) * 16 + wsel * 8 + n3], acc);
        }
    }
    for (int i = t; i < 64 * 17; i += 256) red[i] = 0.f;
    gbar(A.bar, 2);   // S3: wq/bq ready, red zeroed

    // ---- phase B: scores; wq staged through LDS (plain cached float4 x2) ----
    {
        float* wqL = etb;   // overlays etb+ext: 2048 f32 = 128 c x 16 j
        int s = t & 63, g2 = t >> 6;
        int sp = s >> 1, sh = (s & 1) << 4;
        float ak[16];
#pragma unroll
        for (int j = 0; j < 16; ++j) ak[j] = 0.f;
#pragma unroll 1
        for (int cc4 = 0; cc4 < 4; ++cc4) {
            __syncthreads();   // previous chunk fully consumed
            {
                const float* src = A.wq + (((size_t)b * CCn + cc4 * 128) << 4) + t * 8;
                float4 p0 = *reinterpret_cast<const float4*>(src);
                float4 p1 = *reinterpret_cast<const float4*>(src + 4);
                float* dst = wqL + t * 8;
                dst[0] = p0.x; dst[1] = p0.y; dst[2] = p0.z; dst[3] = p0.w;
                dst[4] = p1.x; dst[5] = p1.y; dst[6] = p1.z; dst[7] = p1.w;
            }
            __syncthreads();
#pragma unroll 4
            for (int i = 0; i < 32; ++i) {
                int cl = g2 * 32 + i;
                int r = cc4 * 128 + cl;
                u32 wv = vtd[r * 32 + (sp ^ (r & 31))];
                float vvf = bfr((u16)(wv >> sh));
                const float* wc = wqL + cl * 16;
#pragma unroll
                for (int j = 0; j < 16; ++j) ak[j] += wc[j] * vvf;
            }
        }
#pragma unroll
        for (int j = 0; j < 16; ++j) atomicAdd(&red[s * 17 + j], ak[j]);
    }
    __syncthreads();
    if (t < 64) {
        int s = t;
#pragma unroll
        for (int n = 0; n < NH; ++n) {
            float rc = red[s * 17 + n];
            float rd = red[s * 17 + 8 + n];
            float skc = (rc + A.bq[b * 8 + n]) * 0.125f;
            float skd = (rd + A.bq[256 + b * 8 + n]) * 0.125f;
            etb[s * 8 + n] = __expf(skc);   // |skc| small: no max-subtraction
            cst(&A.dsig[((size_t)(b * NH + n)) * HWn + s0 + s],
                1.f / (1.f + __expf(-skd)));
        }
    }
    __syncthreads();
    if (t < 8) {
        float a = 0.f;
#pragma unroll
        for (int s = 0; s < 64; ++s) a += etb[s * 8 + t];
        cst(&A.sums[(b * NH + t) * 16 + sc], a);
    }
    // ---- phase C: pv partials (thread owns c = t, t+256) ----
    {
        float acc0[NH], acc1[NH];
#pragma unroll
        for (int n = 0; n < NH; ++n) { acc0[n] = 0.f; acc1[n] = 0.f; }
        int c0 = t, c1 = t + 256;
        int m = t & 31;
#pragma unroll 2
        for (int sp = 0; sp < 32; ++sp) {
            u32 w0 = vtd[c0 * 32 + (sp ^ m)];
            u32 w1 = vtd[c1 * 32 + (sp ^ m)];
            float va0 = bfr((u16)(w0 & 0xffffu)), va1 = bfr((u16)(w0 >> 16));
            float vb0 = bfr((u16)(w1 & 0xffffu)), vb1 = bfr((u16)(w1 >> 16));
            float4 e0a = *reinterpret_cast<const float4*>(etb + sp * 16);
            float4 e0b = *reinterpret_cast<const float4*>(etb + sp * 16 + 4);
            float4 e1a = *reinterpret_cast<const float4*>(etb + sp * 16 + 8);
            float4 e1b = *reinterpret_cast<const float4*>(etb + sp * 16 + 12);
            PVACC(acc0, e0a, e0b, va0)
            PVACC(acc0, e1a, e1b, va1)
            PVACC(acc1, e0a, e0b, vb0)
            PVACC(acc1, e1a, e1b, vb1)
        }
        size_t base = ((size_t)sc * BB + b) * NH;
#pragma unroll
        for (int n = 0; n < NH; ++n) {
            cst(&A.pvp[(base + n) * CCn + c0], acc0[n]);
            cst(&A.pvp[(base + n) * CCn + c1], acc1[n]);
        }
    }
    gbar(A.bar, 3);   // S4: pvp, dsig, sums ready

    // ---- k7: combine pv, normalize, attn + A2 (blocks 0..255); plain reads --
    if (bid < 256) {
        int n = bid & 7, b7 = bid >> 3;
        for (int c = t; c < CCn; c += 256) {
            float acc = 0.f;
#pragma unroll 4
            for (int s2 = 0; s2 < 16; ++s2)
                acc += A.pvp[(((size_t)s2 * BB + b7) * NH + n) * CCn + c];
            pvl[c] = acc;
        }
        if (t == 0) {
            float a = 0.f;
#pragma unroll
            for (int s2 = 0; s2 < 16; ++s2)
                a += A.sums[(b7 * NH + n) * 16 + s2];
            sinvp[0] = 1.f / a;
        }
        __syncthreads();
        {
            int d = t & 63, qq = t >> 6;
            const float* wrow = A.wvs + (size_t)(n * DKn + d) * CCn + qq * 128;
            const float* pq = pvl + qq * 128;
            float acc = 0.f;
#pragma unroll 4
            for (int i = 0; i < 128; ++i) acc += pq[i] * wrow[i];
            scr7[d * 5 + qq] = acc;
        }
        __syncthreads();
        if (t < 64) {
            float a = (scr7[t * 5] + scr7[t * 5 + 1] + scr7[t * 5 + 2] + scr7[t * 5 + 3])
                      * sinvp[0] + A.bvs[n * DKn + t];
            cst(&A.attn[(b7 * NH + n) * DKn + t], a);
            al7[t] = a;
        }
        __syncthreads();
        if (t < 9) {
            float acc = 0.f;
#pragma unroll 8
            for (int d2 = 0; d2 < DKn; ++d2)
                acc += al7[d2] * A.wm[(n * DKn + d2) * 9 + t];
            cst(&A.A2g[b7 * 72 + n * 9 + t], acc);
        }
    }
    gbar(A.bar, 4);   // S5: attn, A2g ready

    // ---- k9/k8: outputs. Block covers spatial rows y = 2sc, 2sc+1 ----
    int y0 = sc * 2;
    {
        for (int idx = t; idx < CCn; idx += 256) {
            al[idx] = A.attn[b * CCn + idx];
            float Av = A.gam[idx] * rsqrtf(A.var[idx] + 1e-5f);
            bnA[idx] = Av;
            bnB[idx] = A.bet[idx] - A.mea[idx] * Av;
        }
        for (int idx = t; idx < NH * 64; idx += 256) {
            int n = idx >> 6, r6 = idx & 63;
            int yb2 = r6 >> 5, x = r6 & 31;
            dsl[idx] = A.dsig[((size_t)(b * NH + n)) * HWn + x * 32 + y0 + yb2];
        }
        for (int idx = t; idx < 4 * NH * 32; idx += 256) {
            int ry = idx >> 8, n = (idx >> 5) & 7, x = idx & 31;
            int ycol = y0 - 1 + ry;
            float dvv = 0.f;
            if ((unsigned)ycol < 32u)
                dvv = A.dsig[((size_t)(b * NH + n)) * HWn + x * 32 + ycol];
            k8s[idx] = f2bf(dvv);
        }
        if (t < 72) A2l[t] = A.A2g[b * 72 + t];
    }
    __syncthreads();
    {
        int l = t & 63, wv = t >> 6;
        int csub = l >> 4, yb = (l >> 3) & 1, x0 = (l & 7) * 4;
        int sl = yb * 32 + x0;
#pragma unroll 2
        for (int it = 0; it < 32; ++it) {
            int c = it * 16 + wv * 4 + csub;
            int n = c >> 6;
            int m = c & 31;
            u32 w0 = vtd[c * 32 + ((sl >> 1) ^ m)];
            u32 w1 = vtd[c * 32 + (((sl >> 1) + 1) ^ m)];
            float4 dv = *reinterpret_cast<const float4*>(dsl + n * 64 + sl);
            float a = al[c], Ac = bnA[c], Bc = bnB[c];
            float p0 = a * dv.x, p1 = a * dv.y, p2 = a * dv.z, p3 = a * dv.w;
            size_t ob = (((size_t)(b * CCn + c)) << 10) + (u32)((y0 + yb) * 32 + x0);
            *reinterpret_cast<float4*>(A.out2 + ob) = make_float4(p0, p1, p2, p3);
            float o0 = fmaf(p0, Ac, Bc) + bfr((u16)(w0 & 0xffffu));
            float o1 = fmaf(p1, Ac, Bc) + bfr((u16)(w0 >> 16));
            float o2 = fmaf(p2, Ac, Bc) + bfr((u16)(w1 & 0xffffu));
            float o3 = fmaf(p3, Ac, Bc) + bfr((u16)(w1 >> 16));
            o0 = o0 < 0.f ? 0.1f * o0 : o0;
            o1 = o1 < 0.f ? 0.1f * o1 : o1;
            o2 = o2 < 0.f ? 0.1f * o2 : o2;
            o3 = o3 < 0.f ? 0.1f * o3 : o3;
            *reinterpret_cast<float4*>(A.out0 + ob) = make_float4(o0, o1, o2, o3);
        }
    }
    if (t < 64) {
        int y = y0 + (t >> 5), x = t & 31;
        float msum = 0.f;
#pragma unroll
        for (int n = 0; n < NH; ++n) {
#pragma unroll
            for (int dy = 0; dy < 3; ++dy) {
                int ry = (t >> 5) + dy;
#pragma unroll
                for (int dx = 0; dx < 3; ++dx) {
                    int xx = x + dx - 1;
                    if ((unsigned)xx < 32u)
                        msum += A2l[n * 9 + dy * 3 + dx] * bfr(k8s[ry * 256 + n * 32 + xx]);
                }
            }
        }
        A.out1[b * HWn + y * 32 + x] = msum + A.wmb[0];
    }
}

// ===========================================================================
// Fallback path: proven 7-kernel pipeline (347 us)
// ===========================================================================

__global__ void k1_qsum_pre(const float* __restrict__ q, float* __restrict__ qsp) {
    int b = blockIdx.y;
    int dq = blockIdx.x * 256 + threadIdx.x;
    const float* qp = q + (size_t)b * LL * DQn + dq;
    float acc = 0.f;
#pragma unroll 8
    for (int l = 0; l < LL; ++l) acc += qp[l * DQn];
    qsp[b * DQn + dq] = acc;
}

__global__ void k2_qsum(const float* __restrict__ qsp, const float* __restrict__ w,
                        const float* __restrict__ bias, float* __restrict__ qs) {
    int dof = blockIdx.x;
    int t = threadIdx.x;
    int b = t & 31, ch = t >> 5;
    const float* wrow = w + (size_t)dof * DQn + ch * 128;
    const float* qrow = qsp + (size_t)b * DQn + ch * 128;
    float acc = 0.f;
#pragma unroll 8
    for (int i = 0; i < 128; i += 4) {
        float4 wv = *reinterpret_cast<const float4*>(wrow + i);
        float4 qv = *reinterpret_cast<const float4*>(qrow + i);
        acc += wv.x * qv.x + wv.y * qv.y + wv.z * qv.z + wv.w * qv.w;
    }
    __shared__ float scr[256];
    scr[t] = acc;
    __syncthreads();
    if (t < 32) {
        float a = 0.f;
#pragma unroll
        for (int c2 = 0; c2 < 8; ++c2) a += scr[c2 * 32 + t];
        qs[t * CCn + dof] = a + 64.f * bias[dof];
    }
}

__global__ void k3_wq(const float* __restrict__ qs,
                      const float* __restrict__ wkc, const float* __restrict__ bkc,
                      const float* __restrict__ wkd, const float* __restrict__ bkd,
                      float* __restrict__ wq, float* __restrict__ bq) {
    int cc = blockIdx.x, wsel = blockIdx.y, b = blockIdx.z;
    const float* w = wsel ? wkd : wkc;
    int cl = threadIdx.x & 31, n = threadIdx.x >> 5;
    int c = cc * 32 + cl;
    const float* qrow = qs + b * CCn + n * DKn;
    const float* wrow = w + (size_t)(n * DKn) * CCn + c;
    float acc = 0.f;
#pragma unroll 8
    for (int d = 0; d < DKn; ++d)
        acc += qrow[d] * wrow[(size_t)d * CCn];
    wq[((size_t)b * CCn + c) * 16 + wsel * 8 + n] = acc;
    if (cc == 0 && b == 0) {
        const float* bw = wsel ? bkd : bkc;
        int pp = threadIdx.x, bb = pp >> 3, nn = pp & 7;
        float a2 = 0.f;
#pragma unroll 8
        for (int d = 0; d < DKn; ++d)
            a2 += qs[bb * CCn + nn * DKn + d] * bw[nn * DKn + d];
        bq[wsel * 256 + pp] = a2;
    }
}

__global__ void __launch_bounds__(256) k46_scorepv(
        const float* __restrict__ v, const float* __restrict__ wq,
        const float* __restrict__ bq, float* __restrict__ dsig,
        float* __restrict__ pvp, float* __restrict__ sums) {
    int sc = blockIdx.x, b = blockIdx.y;
    __shared__ u16 vt[CCn * 33];
    __shared__ float red[4][32][17];
    __shared__ float et[32 * 8];
    int t = threadIdx.x;
    int s0 = sc * 32;
    {
        int s = t & 31, c2 = t >> 5;
        const float* vb = v + ((size_t)(b * CCn + c2 * 64) << 10) + s0 + s;
#pragma unroll 8
        for (int cr = 0; cr < 64; ++cr)
            vt[(c2 * 64 + cr) * 33 + s] = f2bf(vb[(size_t)cr << 10]);
    }
    __syncthreads();
    {
        int s = t & 31, g = t >> 5;
        float ak[16];
#pragma unroll
        for (int j = 0; j < 16; ++j) ak[j] = 0.f;
        const float* wqb = wq + ((size_t)b * CCn + g * 64) * 16;
#pragma unroll 4
        for (int i = 0; i < 64; ++i) {
            float vv = bfr(vt[(g * 64 + i) * 33 + s]);
            const float* wc = wqb + i * 16;
#pragma unroll
            for (int j = 0; j < 16; ++j) ak[j] += wc[j] * vv;
        }
#pragma unroll
        for (int j = 0; j < 16; ++j) ak[j] += __shfl_xor(ak[j], 32);
        int wv = t >> 6;
        if ((t & 63) < 32) {
#pragma unroll
            for (int j = 0; j < 16; ++j) red[wv][s][j] = ak[j];
        }
    }
    __syncthreads();
    if (t < 32) {
        int s = t;
#pragma unroll
        for (int n = 0; n < NH; ++n) {
            float rc = red[0][s][n] + red[1][s][n] + red[2][s][n] + red[3][s][n];
            float rd = red[0][s][8 + n] + red[1][s][8 + n] + red[2][s][8 + n] + red[3][s][8 + n];
            float skc = (rc + bq[b * 8 + n]) * 0.125f;
            float skd = (rd + bq[256 + b * 8 + n]) * 0.125f;
            et[s * 8 + n] = __expf(skc);
            dsig[(b * NH + n) * HWn + s0 + s] = 1.f / (1.f + __expf(-skd));
        }
    }
    __syncthreads();
    if (t < 8) {
        float a = 0.f;
#pragma unroll
        for (int s = 0; s < 32; ++s) a += et[s * 8 + t];
        sums[(b * NH + t) * 32 + sc] = a;
    }
    {
        float acc0[NH], acc1[NH];
#pragma unroll
        for (int n = 0; n < NH; ++n) { acc0[n] = 0.f; acc1[n] = 0.f; }
#pragma unroll 2
        for (int s = 0; s < 32; ++s) {
            float4 ea = *reinterpret_cast<const float4*>(et + s * 8);
            float4 eb = *reinterpret_cast<const float4*>(et + s * 8 + 4);
            float va = bfr(vt[t * 33 + s]);
            float vb2 = bfr(vt[(t + 256) * 33 + s]);
            acc0[0] += ea.x * va; acc0[1] += ea.y * va; acc0[2] += ea.z * va; acc0[3] += ea.w * va;
            acc0[4] += eb.x * va; acc0[5] += eb.y * va; acc0[6] += eb.z * va; acc0[7] += eb.w * va;
            acc1[0] += ea.x * vb2; acc1[1] += ea.y * vb2; acc1[2] += ea.z * vb2; acc1[3] += ea.w * vb2;
            acc1[4] += eb.x * vb2; acc1[5] += eb.y * vb2; acc1[6] += eb.z * vb2; acc1[7] += eb.w * vb2;
        }
        size_t base = ((size_t)sc * BB + b) * NH;
#pragma unroll
        for (int n = 0; n < NH; ++n) {
            pvp[(base + n) * CCn + t] = acc0[n];
            pvp[(base + n) * CCn + t + 256] = acc1[n];
        }
    }
}

__global__ void k7_attn(const float* __restrict__ pvp, const float* __restrict__ sums,
                        const float* __restrict__ wvs, const float* __restrict__ bvs,
                        float* __restrict__ attn) {
    int n = blockIdx.x, b = blockIdx.y;
    __shared__ float pvl[CCn];
    __shared__ float scr[64 * 5];
    __shared__ float sinv;
    int t = threadIdx.x;
    if (t == 0) {
        float a = 0.f;
#pragma unroll
        for (int sc = 0; sc < 32; ++sc) a += sums[(b * NH + n) * 32 + sc];
        sinv = 1.f / a;
    }
    for (int c = t; c < CCn; c += 256) {
        float acc = 0.f;
#pragma unroll 4
        for (int sc = 0; sc < 32; ++sc)
            acc += pvp[(((size_t)sc * BB + b) * NH + n) * CCn + c];
        pvl[c] = acc;
    }
    __syncthreads();
    int d = t & 63, qq = t >> 6;
    const float* wrow = wvs + (size_t)(n * DKn + d) * CCn + qq * 128;
    const float* pq = pvl + qq * 128;
    float acc = 0.f;
#pragma unroll 4
    for (int i = 0; i < 128; ++i) acc += pq[i] * wrow[i];
    scr[d * 5 + qq] = acc;
    __syncthreads();
    if (t < 64) {
        float a = (scr[t * 5] + scr[t * 5 + 1] + scr[t * 5 + 2] + scr[t * 5 + 3]) * sinv
                + bvs[n * DKn + t];
        attn[(b * NH + n) * DKn + t] = a;
    }
}

__global__ void k8_mattn(const float* __restrict__ dsig, const float* __restrict__ attn,
                         const float* __restrict__ wm, const float* __restrict__ wmb,
                         float* __restrict__ out1) {
    int b = blockIdx.x;
    __shared__ float dst[NH * 1056];
    __shared__ float al[CCn];
    __shared__ float A2[NH * 9];
    int t = threadIdx.x;
    al[t] = attn[b * CCn + t];
    al[t + 256] = attn[b * CCn + t + 256];
    for (int g = t; g < NH * HWn; g += 256) {
        int n = g >> 10, s = g & 1023;
        dst[n * 1056 + (s & 31) * 33 + (s >> 5)] = dsig[b * NH * HWn + g];
    }
    __syncthreads();
    if (t < 72) {
        int n = t / 9, tap = t % 9;
        float acc = 0.f;
#pragma unroll 8
        for (int d = 0; d < DKn; ++d)
            acc += al[n * DKn + d] * wm[(n * DKn + d) * 9 + tap];
        A2[t] = acc;
    }
    __syncthreads();
    float bm = wmb[0];
    for (int pos = t; pos < HWn; pos += 256) {
        int y = pos >> 5, x = pos & 31;
        float m = 0.f;
#pragma unroll
        for (int n = 0; n < NH; ++n) {
            const float* dn = dst + n * 1056;
#pragma unroll
            for (int dy = 0; dy < 3; ++dy) {
                int yy = y + dy - 1;
                if ((unsigned)yy < 32u) {
#pragma unroll
                    for (int dx = 0; dx < 3; ++dx) {
                        int xx = x + dx - 1;
                        if ((unsigned)xx < 32u)
                            m += A2[n * 9 + dy * 3 + dx] * dn[yy * 33 + xx];
                    }
                }
            }
        }
        out1[b * HWn + pos] = m + bm;
    }
}

__global__ void __launch_bounds__(256) k9_out(
        const float* __restrict__ v, const float* __restrict__ dsig,
        const float* __restrict__ attn,
        const float* __restrict__ gamma, const float* __restrict__ beta,
        const float* __restrict__ mean, const float* __restrict__ var,
        float* __restrict__ out0, float* __restrict__ out2) {
    int dh = blockIdx.x, n = blockIdx.y, b = blockIdx.z;
    __shared__ float dst[1056];
    __shared__ float al[16], bnA[16], bnB[16];
    int t = threadIdx.x;
#pragma unroll
    for (int k = 0; k < 4; ++k) {
        int s = t + k * 256;
        dst[(s & 31) * 33 + (s >> 5)] = dsig[(b * NH + n) * HWn + s];
    }
    if (t < 16) {
        int d = dh * 16 + t;
        al[t] = attn[(b * NH + n) * DKn + d];
        int ch = n * DKn + d;
        float A = gamma[ch] * rsqrtf(var[ch] + 1e-5f);
        bnA[t] = A;
        bnB[t] = beta[ch] - mean[ch] * A;
    }
    __syncthreads();
    int y = t >> 3, x = (t & 7) * 4;
    const float* dr = dst + y * 33 + x;
#pragma unroll 2
    for (int k = 0; k < 16; ++k) {
        int d = dh * 16 + k;
        size_t base = (((size_t)(b * CCn + n * DKn + d)) << 10) + y * 32 + x;
        float4 v4 = *reinterpret_cast<const float4*>(v + base);
        float a = al[k], A = bnA[k], Bc = bnB[k];
        float p0 = a * dr[0], p1 = a * dr[1], p2 = a * dr[2], p3 = a * dr[3];
        float4 mo = make_float4(p0, p1, p2, p3);
        *reinterpret_cast<float4*>(out2 + base) = mo;
        float o0 = p0 * A + Bc + v4.x;
        float o1 = p1 * A + Bc + v4.y;
        float o2 = p2 * A + Bc + v4.z;
        float o3 = p3 * A + Bc + v4.w;
        o0 = o0 < 0.f ? 0.1f * o0 : o0;
        o1 = o1 < 0.f ? 0.1f * o1 : o1;
        o2 = o2 < 0.f ? 0.1f * o2 : o2;
        o3 = o3 < 0.f ? 0.1f * o3 : o3;
        float4 oo = make_float4(o0, o1, o2, o3);
        *reinterpret_cast<float4*>(out0 + base) = oo;
    }
}

extern "C" void kernel_launch(void* const* d_in, const int* in_sizes, int n_in,
                              void* d_out, int out_size, void* d_ws, size_t ws_size,
                              hipStream_t stream) {
    (void)in_sizes; (void)n_in; (void)out_size; (void)ws_size;
    const float* q   = (const float*)d_in[0];
    const float* v   = (const float*)d_in[1];
    const float* wqs = (const float*)d_in[3];
    const float* bqs = (const float*)d_in[4];
    const float* wkc = (const float*)d_in[7];
    const float* bkc = (const float*)d_in[8];
    const float* wkd = (const float*)d_in[9];
    const float* bkd = (const float*)d_in[10];
    const float* wvs = (const float*)d_in[11];
    const float* bvs = (const float*)d_in[12];
    const float* wm  = (const float*)d_in[13];
    const float* wmb = (const float*)d_in[14];
    const float* gam = (const float*)d_in[15];
    const float* bet = (const float*)d_in[16];
    const float* mea = (const float*)d_in[17];
    const float* var = (const float*)d_in[18];

    float* ws = (float*)d_ws;
    float* out0 = (float*)d_out;        // (32,512,32,32)
    float* out1 = out0 + 16777216;      // (32,1024)
    float* out2 = out1 + 32768;         // (32,512,32,32)

    static int mode = -1;
    if (mode < 0) {
        hipError_t e = hipFuncSetAttribute(reinterpret_cast<const void*>(mega),
                                           hipFuncAttributeMaxDynamicSharedMemorySize,
                                           POOLB);
        mode = (e == hipSuccess) ? 1 : 0;
    }

    if (mode == 1) {
        MArgs a;
        a.q = q; a.v = v; a.wqs = wqs; a.bqs = bqs; a.wkc = wkc; a.bkc = bkc;
        a.wkd = wkd; a.bkd = bkd; a.wvs = wvs; a.bvs = bvs; a.wm = wm; a.wmb = wmb;
        a.gam = gam; a.bet = bet; a.mea = mea; a.var = var;
        a.qsp  = ws;            //  32768
        a.qs   = ws + 32768;    //  16384
        a.wq   = ws + 49152;    // 262144
        a.bq   = ws + 311296;   //     512
        a.dsig = ws + 311808;   //  262144
        a.sums = ws + 573952;   //    4096 (32*8*16)
        a.attn = ws + 578048;   //   16384
        a.A2g  = ws + 594432;   //    2304
        a.pvp  = ws + 596736;   // 2097152 (16 chunks)
        a.bar  = (u32*)(ws + 2693888);  // 16 flags + 512*16 slot words
        a.out0 = out0; a.out1 = out1; a.out2 = out2;
        kinit<<<dim3(8), dim3(256), 0, stream>>>(a.bar);
        mega<<<dim3(NBLK), dim3(256), POOLB, stream>>>(a);
        return;
    }

    // ---- fallback: proven 7-kernel pipeline ----
    float* qsp  = ws + 0;
    float* qs   = ws + 32768;
    float* wq   = ws + 49152;
    float* bq   = ws + 311296;
    float* dsig = ws + 311808;
    float* sums = ws + 573952;
    float* attn = ws + 582144;
    float* pvp  = ws + 598528;

    k1_qsum_pre<<<dim3(4, 32), 256, 0, stream>>>(q, qsp);
    k2_qsum<<<dim3(512), 256, 0, stream>>>(qsp, wqs, bqs, qs);
    k3_wq<<<dim3(16, 2, 32), 256, 0, stream>>>(qs, wkc, bkc, wkd, bkd, wq, bq);
    k46_scorepv<<<dim3(32, 32), 256, 0, stream>>>(v, wq, bq, dsig, pvp, sums);
    k7_attn<<<dim3(8, 32), 256, 0, stream>>>(pvp, sums, wvs, bvs, attn);
    k8_mattn<<<dim3(32), 256, 0, stream>>>(dsig, attn, wm, wmb, out1);
    k9_out<<<dim3(4, 8, 32), 256, 0, stream>>>(v, dsig, attn, gam, bet, mea, var, out0, out2);
}

// Round 8
// 323.637 us; speedup vs baseline: 1.2408x; 1.2408x over previous
//
#include <hip/hip_runtime.h>

// GaranAttentionV2: b=32, l=64, d_q=1024, c=d_o=512, n_head=8, dk=64, h=w=32, hw=1024
// R12: PER-B SUB-BARRIERS. Key insight: b is a batch dim -- NO intermediate
// crosses b. Re-decomposing k1/k2 per-b makes all 5 grid barriers independent
// 16-block group barriers (epoch slots, lane-parallel poll, no detector).
// Coherence: ONE acquire fence at kernel entry (drops prior-replay stale
// lines); intermediates written via write-through agent atomics (L2 never
// dirty) and read via PLAIN cached coalesced loads (safe: no region is read
// before its producing barrier -> no intra-kernel stale copy; all per-b
// regions 128B-line padded/aligned: bq stride 32, A2g stride 96).
// R11's per-barrier fence (regression, -29us) removed. Bounded spins.
// Fallback (attr failure): proven 7-kernel path (347us).

#define BB 32
#define LL 64
#define DQn 1024
#define CCn 512
#define NH 8
#define DKn 64
#define HWn 1024
#define NBLK 512
#define SLOTSTRIDE 16   // u32s; 64B between slots (atomic path, L2-bypassing)

typedef unsigned short u16;
typedef unsigned int u32;
typedef unsigned long long u64;

__device__ __forceinline__ float bfr(u16 u) {
    return __uint_as_float(((u32)u) << 16);
}
__device__ __forceinline__ u16 f2bf(float f) {
    u32 x = __float_as_uint(f);
    u32 r = (x + 0x7FFFu + ((x >> 16) & 1u)) >> 16;
    return (u16)r;
}

// Write-through (LLC-coherent) stores for cross-block intermediates.
__device__ __forceinline__ void cst(float* p, float v) {
    __hip_atomic_store(p, v, __ATOMIC_RELAXED, __HIP_MEMORY_SCOPE_AGENT);
}
__device__ __forceinline__ u32 cldu(const u32* p) {
    return __hip_atomic_load(const_cast<u32*>(p), __ATOMIC_RELAXED,
                             __HIP_MEMORY_SCOPE_AGENT);
}
__device__ __forceinline__ void cstu(u32* p, u32 v) {
    __hip_atomic_store(p, v, __ATOMIC_RELAXED, __HIP_MEMORY_SCOPE_AGENT);
}

// ---------------------------------------------------------------------------
#define POOLB 78080

struct MArgs {
    const float *q, *v, *wqs, *bqs, *wkc, *bkc, *wkd, *bkd, *wvs, *bvs, *wm, *wmb,
                *gam, *bet, *mea, *var;
    float *qsp, *qs, *wq, *bq, *dsig, *sums, *attn, *A2g, *pvp;
    u32* bar;   // slots[bid*SLOTSTRIDE], bid = b*16+sc
    float *out0, *out1, *out2;
};

// Per-b group barrier: 16 blocks (sc 0..15 of batch b). Arrive = epoch store
// to own slot; every block polls its group's 16 slots lane-parallel (lanes
// 0..15). No detector, no release flag. __syncthreads drains write-through
// stores (at LLC once vmcnt retires). Bounded: wrong answer, never a hang.
__device__ __forceinline__ void gbarb(u32* slots, int b, int sc, int i) {
    u32 epoch = (u32)(i + 1);
    __syncthreads();
    int t = threadIdx.x;
    if (t < 64) {
        if (t == 0) cstu(&slots[(b * 16 + sc) * SLOTSTRIDE], epoch);
        int it = 0;
        for (;;) {
            bool ok = true;
            if (t < 16)
                ok = (cldu(&slots[(b * 16 + t) * SLOTSTRIDE]) >= epoch);
            if (__all(ok)) break;
            __builtin_amdgcn_s_sleep(1);
            if (++it > (1 << 17)) break;   // failsafe
        }
    }
    __syncthreads();
}

__global__ void kinit(u32* bar) {
    int t = threadIdx.x + blockIdx.x * blockDim.x;
    int total = NBLK * SLOTSTRIDE;
    for (int i = t; i < total; i += blockDim.x * gridDim.x)
        cstu(&bar[i], 0u);
}

#define PVACC(accv, eA, eB, vf) \
    accv[0] += eA.x * (vf); accv[1] += eA.y * (vf); accv[2] += eA.z * (vf); accv[3] += eA.w * (vf); \
    accv[4] += eB.x * (vf); accv[5] += eB.y * (vf); accv[6] += eB.z * (vf); accv[7] += eB.w * (vf);

// LDS pool: vtd[0,65536) u32[512*32] | red[65536,69888) f32[64*17]
//           etb[69888,71936) f32[64*8] | ext[71936,78080) f32[1536]
// Phase-B wqL chunk buffer overlays etb+ext: [69888,78080) = 2048 f32.
__global__ void __launch_bounds__(256, 2) mega(MArgs A) {
    __builtin_amdgcn_fence(__ATOMIC_ACQUIRE, "agent");   // entry: drop stale L1/L2
    extern __shared__ char pool[];
    u32*   vtd = (u32*)pool;
    float* red = (float*)(pool + 65536);
    float* etb = (float*)(pool + 69888);
    float* ext = (float*)(pool + 71936);
    float* pvl   = etb;
    float* scr7  = red;
    float* al7   = red + 320;
    float* sinvp = red + 384;
    float* dsl   = red;
    float* A2l   = red + 512;
    u16*   k8s   = (u16*)etb;
    float* al    = ext;
    float* bnA   = ext + 512;
    float* bnB   = ext + 1024;

    int t = threadIdx.x;
    int bid = blockIdx.x;
    int sc = bid & 15, b = bid >> 4;
    int s0 = sc * 64;
    u32* slots = A.bar;

    // ---- k1 slice: qsp[b, sc*64 .. +64] = sum_l q[b,l,dq] ----
    {
        int dqo = t & 63, lq = t >> 6;
        const float* qp = A.q + (size_t)b * (LL * DQn) + (size_t)(lq * 16) * DQn
                        + sc * 64 + dqo;
        float acc = 0.f;
#pragma unroll
        for (int l = 0; l < 16; ++l) acc += qp[(size_t)l * DQn];
        red[dqo * 4 + lq] = acc;
    }
    __syncthreads();
    if (t < 64) {
        float a = red[t * 4] + red[t * 4 + 1] + red[t * 4 + 2] + red[t * 4 + 3];
        cst(&A.qsp[b * DQn + sc * 64 + t], a);
    }

    // ---- phase A: stage v chunk (512 c x 64 s) into LDS bf16, swizzled ----
    {
        int sp = t & 31, c2 = t >> 5;
        const float* vb = A.v + (((size_t)(b * CCn + c2 * 64)) << 10) + s0 + sp * 2;
#pragma unroll 8
        for (int cr = 0; cr < 64; ++cr) {
            int r = c2 * 64 + cr;
            float2 xv = *reinterpret_cast<const float2*>(vb + ((size_t)cr << 10));
            u32 w = (u32)f2bf(xv.x) | ((u32)f2bf(xv.y) << 16);
            vtd[r * 32 + (sp ^ (r & 31))] = w;
        }
    }
    gbarb(slots, b, sc, 0);   // S1b: qsp[b] ready

    // ---- k2 slice: qs[b, sc*32 + (t>>3)] (8-lane split over dq) ----
    {
        int dof = sc * 32 + (t >> 3);
        int part = t & 7;
        const float* qrow = A.qsp + b * DQn + part * 128;
        const float* wrow = A.wqs + (size_t)dof * DQn + part * 128;
        float acc = 0.f;
#pragma unroll 8
        for (int i = 0; i < 128; i += 4) {
            float4 qv = *reinterpret_cast<const float4*>(qrow + i);
            float4 wv = *reinterpret_cast<const float4*>(wrow + i);
            acc += wv.x * qv.x + wv.y * qv.y + wv.z * qv.z + wv.w * qv.w;
        }
        acc += __shfl_xor(acc, 4);
        acc += __shfl_xor(acc, 2);
        acc += __shfl_xor(acc, 1);
        if (part == 0) cst(&A.qs[b * CCn + dof], acc + 64.f * A.bqs[dof]);
    }
    gbarb(slots, b, sc, 1);   // S2b: qs[b] ready

    // ---- stage qs[b][*] into etb (plain cached) ----
    {
        float2 p = *reinterpret_cast<const float2*>(&A.qs[b * CCn + t * 2]);
        etb[t * 2] = p.x; etb[t * 2 + 1] = p.y;
    }
    __syncthreads();

    // ---- bq: sc==0 block of each group (own b, from LDS qs); stride 32 ----
    if (sc == 0 && t < 16) {
        int wsel = t >> 3, n = t & 7;
        const float* bw = wsel ? A.bkd : A.bkc;
        float a2 = 0.f;
#pragma unroll 8
        for (int d = 0; d < DKn; ++d)
            a2 += etb[n * DKn + d] * bw[n * DKn + d];
        cst(&A.bq[b * 32 + wsel * 8 + n], a2);
    }

    // ---- k3: wq coefficients (c = sc*32..+32, both wsel); qs from LDS ----
    {
        int cl = t & 31, n3 = t >> 5;
        int c = sc * 32 + cl;
#pragma unroll
        for (int wsel = 0; wsel < 2; ++wsel) {
            const float* w = wsel ? A.wkd : A.wkc;
            const float* qrow = etb + n3 * DKn;
            const float* wrow = w + (size_t)(n3 * DKn) * CCn + c;
            float acc = 0.f;
#pragma unroll 8
            for (int d = 0; d < DKn; ++d) acc += qrow[d] * wrow[(size_t)d * CCn];
            cst(&A.wq[((size_t)b * CCn + c) * 16 + wsel * 8 + n3], acc);
        }
    }
    for (int i = t; i < 64 * 17; i += 256) red[i] = 0.f;
    gbarb(slots, b, sc, 2);   // S3b: wq[b]/bq[b] ready, red zeroed

    // ---- phase B: scores; wq[b] staged through LDS in 4 chunks of 128 c ----
    {
        float* wqL = etb;   // overlays etb+ext: 2048 f32 = 128 c x 16 j
        int s = t & 63, g2 = t >> 6;
        int sp = s >> 1, sh = (s & 1) << 4;
        float ak[16];
#pragma unroll
        for (int j = 0; j < 16; ++j) ak[j] = 0.f;
#pragma unroll 1
        for (int cc4 = 0; cc4 < 4; ++cc4) {
            __syncthreads();   // previous chunk fully consumed
            {
                const float* src = A.wq + (((size_t)b * CCn + cc4 * 128) << 4) + t * 8;
                float4 p0 = *reinterpret_cast<const float4*>(src);
                float4 p1 = *reinterpret_cast<const float4*>(src + 4);
                float* dst = wqL + t * 8;
                dst[0] = p0.x; dst[1] = p0.y; dst[2] = p0.z; dst[3] = p0.w;
                dst[4] = p1.x; dst[5] = p1.y; dst[6] = p1.z; dst[7] = p1.w;
            }
            __syncthreads();
#pragma unroll 4
            for (int i = 0; i < 32; ++i) {
                int cl = g2 * 32 + i;
                int r = cc4 * 128 + cl;
                u32 wv = vtd[r * 32 + (sp ^ (r & 31))];
                float vvf = bfr((u16)(wv >> sh));
                const float* wc = wqL + cl * 16;
#pragma unroll
                for (int j = 0; j < 16; ++j) ak[j] += wc[j] * vvf;
            }
        }
#pragma unroll
        for (int j = 0; j < 16; ++j) atomicAdd(&red[s * 17 + j], ak[j]);
    }
    __syncthreads();
    if (t < 64) {
        int s = t;
#pragma unroll
        for (int n = 0; n < NH; ++n) {
            float rc = red[s * 17 + n];
            float rd = red[s * 17 + 8 + n];
            float skc = (rc + A.bq[b * 32 + n]) * 0.125f;
            float skd = (rd + A.bq[b * 32 + 8 + n]) * 0.125f;
            etb[s * 8 + n] = __expf(skc);   // |skc| small: no max-subtraction
            cst(&A.dsig[((size_t)(b * NH + n)) * HWn + s0 + s],
                1.f / (1.f + __expf(-skd)));
        }
    }
    __syncthreads();
    if (t < 8) {
        float a = 0.f;
#pragma unroll
        for (int s = 0; s < 64; ++s) a += etb[s * 8 + t];
        cst(&A.sums[(b * NH + t) * 16 + sc], a);
    }
    // ---- phase C: pv partials (thread owns c = t, t+256) ----
    {
        float acc0[NH], acc1[NH];
#pragma unroll
        for (int n = 0; n < NH; ++n) { acc0[n] = 0.f; acc1[n] = 0.f; }
        int c0 = t, c1 = t + 256;
        int m = t & 31;
#pragma unroll 2
        for (int sp = 0; sp < 32; ++sp) {
            u32 w0 = vtd[c0 * 32 + (sp ^ m)];
            u32 w1 = vtd[c1 * 32 + (sp ^ m)];
            float va0 = bfr((u16)(w0 & 0xffffu)), va1 = bfr((u16)(w0 >> 16));
            float vb0 = bfr((u16)(w1 & 0xffffu)), vb1 = bfr((u16)(w1 >> 16));
            float4 e0a = *reinterpret_cast<const float4*>(etb + sp * 16);
            float4 e0b = *reinterpret_cast<const float4*>(etb + sp * 16 + 4);
            float4 e1a = *reinterpret_cast<const float4*>(etb + sp * 16 + 8);
            float4 e1b = *reinterpret_cast<const float4*>(etb + sp * 16 + 12);
            PVACC(acc0, e0a, e0b, va0)
            PVACC(acc0, e1a, e1b, va1)
            PVACC(acc1, e0a, e0b, vb0)
            PVACC(acc1, e1a, e1b, vb1)
        }
        size_t base = ((size_t)sc * BB + b) * NH;
#pragma unroll
        for (int n = 0; n < NH; ++n) {
            cst(&A.pvp[(base + n) * CCn + c0], acc0[n]);
            cst(&A.pvp[(base + n) * CCn + c1], acc1[n]);
        }
    }
    gbarb(slots, b, sc, 3);   // S4b: pvp/dsig/sums for b ready

    // ---- k7: blocks sc<8 of each group; n = sc ----
    if (sc < 8) {
        int n = sc;
        for (int c = t; c < CCn; c += 256) {
            float acc = 0.f;
#pragma unroll 4
            for (int s2 = 0; s2 < 16; ++s2)
                acc += A.pvp[(((size_t)s2 * BB + b) * NH + n) * CCn + c];
            pvl[c] = acc;
        }
        if (t == 0) {
            float a = 0.f;
#pragma unroll
            for (int s2 = 0; s2 < 16; ++s2)
                a += A.sums[(b * NH + n) * 16 + s2];
            sinvp[0] = 1.f / a;
        }
        __syncthreads();
        {
            int d = t & 63, qq = t >> 6;
            const float* wrow = A.wvs + (size_t)(n * DKn + d) * CCn + qq * 128;
            const float* pq = pvl + qq * 128;
            float acc = 0.f;
#pragma unroll 4
            for (int i = 0; i < 128; ++i) acc += pq[i] * wrow[i];
            scr7[d * 5 + qq] = acc;
        }
        __syncthreads();
        if (t < 64) {
            float a = (scr7[t * 5] + scr7[t * 5 + 1] + scr7[t * 5 + 2] + scr7[t * 5 + 3])
                      * sinvp[0] + A.bvs[n * DKn + t];
            cst(&A.attn[(b * NH + n) * DKn + t], a);
            al7[t] = a;
        }
        __syncthreads();
        if (t < 9) {
            float acc = 0.f;
#pragma unroll 8
            for (int d2 = 0; d2 < DKn; ++d2)
                acc += al7[d2] * A.wm[(n * DKn + d2) * 9 + t];
            cst(&A.A2g[b * 96 + n * 9 + t], acc);
        }
    }
    gbarb(slots, b, sc, 4);   // S5b: attn[b], A2g[b] ready

    // ---- k9/k8: outputs. Block covers spatial rows y = 2sc, 2sc+1 ----
    int y0 = sc * 2;
    {
        for (int idx = t; idx < CCn; idx += 256) {
            al[idx] = A.attn[b * CCn + idx];
            float Av = A.gam[idx] * rsqrtf(A.var[idx] + 1e-5f);
            bnA[idx] = Av;
            bnB[idx] = A.bet[idx] - A.mea[idx] * Av;
        }
        for (int idx = t; idx < NH * 64; idx += 256) {
            int n = idx >> 6, r6 = idx & 63;
            int yb2 = r6 >> 5, x = r6 & 31;
            dsl[idx] = A.dsig[((size_t)(b * NH + n)) * HWn + x * 32 + y0 + yb2];
        }
        for (int idx = t; idx < 4 * NH * 32; idx += 256) {
            int ry = idx >> 8, n = (idx >> 5) & 7, x = idx & 31;
            int ycol = y0 - 1 + ry;
            float dvv = 0.f;
            if ((unsigned)ycol < 32u)
                dvv = A.dsig[((size_t)(b * NH + n)) * HWn + x * 32 + ycol];
            k8s[idx] = f2bf(dvv);
        }
        if (t < 72) A2l[t] = A.A2g[b * 96 + t];
    }
    __syncthreads();
    {
        int l = t & 63, wv = t >> 6;
        int csub = l >> 4, yb = (l >> 3) & 1, x0 = (l & 7) * 4;
        int sl = yb * 32 + x0;
#pragma unroll 2
        for (int it = 0; it < 32; ++it) {
            int c = it * 16 + wv * 4 + csub;
            int n = c >> 6;
            int m = c & 31;
            u32 w0 = vtd[c * 32 + ((sl >> 1) ^ m)];
            u32 w1 = vtd[c * 32 + (((sl >> 1) + 1) ^ m)];
            float4 dv = *reinterpret_cast<const float4*>(dsl + n * 64 + sl);
            float a = al[c], Ac = bnA[c], Bc = bnB[c];
            float p0 = a * dv.x, p1 = a * dv.y, p2 = a * dv.z, p3 = a * dv.w;
            size_t ob = (((size_t)(b * CCn + c)) << 10) + (u32)((y0 + yb) * 32 + x0);
            *reinterpret_cast<float4*>(A.out2 + ob) = make_float4(p0, p1, p2, p3);
            float o0 = fmaf(p0, Ac, Bc) + bfr((u16)(w0 & 0xffffu));
            float o1 = fmaf(p1, Ac, Bc) + bfr((u16)(w0 >> 16));
            float o2 = fmaf(p2, Ac, Bc) + bfr((u16)(w1 & 0xffffu));
            float o3 = fmaf(p3, Ac, Bc) + bfr((u16)(w1 >> 16));
            o0 = o0 < 0.f ? 0.1f * o0 : o0;
            o1 = o1 < 0.f ? 0.1f * o1 : o1;
            o2 = o2 < 0.f ? 0.1f * o2 : o2;
            o3 = o3 < 0.f ? 0.1f * o3 : o3;
            *reinterpret_cast<float4*>(A.out0 + ob) = make_float4(o0, o1, o2, o3);
        }
    }
    if (t < 64) {
        int y = y0 + (t >> 5), x = t & 31;
        float msum = 0.f;
#pragma unroll
        for (int n = 0; n < NH; ++n) {
#pragma unroll
            for (int dy = 0; dy < 3; ++dy) {
                int ry = (t >> 5) + dy;
#pragma unroll
                for (int dx = 0; dx < 3; ++dx) {
                    int xx = x + dx - 1;
                    if ((unsigned)xx < 32u)
                        msum += A2l[n * 9 + dy * 3 + dx] * bfr(k8s[ry * 256 + n * 32 + xx]);
                }
            }
        }
        A.out1[b * HWn + y * 32 + x] = msum + A.wmb[0];
    }
}

// ===========================================================================
// Fallback path: proven 7-kernel pipeline (347 us)
// ===========================================================================

__global__ void k1_qsum_pre(const float* __restrict__ q, float* __restrict__ qsp) {
    int b = blockIdx.y;
    int dq = blockIdx.x * 256 + threadIdx.x;
    const float* qp = q + (size_t)b * LL * DQn + dq;
    float acc = 0.f;
#pragma unroll 8
    for (int l = 0; l < LL; ++l) acc += qp[l * DQn];
    qsp[b * DQn + dq] = acc;
}

__global__ void k2_qsum(const float* __restrict__ qsp, const float* __restrict__ w,
                        const float* __restrict__ bias, float* __restrict__ qs) {
    int dof = blockIdx.x;
    int t = threadIdx.x;
    int b = t & 31, ch = t >> 5;
    const float* wrow = w + (size_t)dof * DQn + ch * 128;
    const float* qrow = qsp + (size_t)b * DQn + ch * 128;
    float acc = 0.f;
#pragma unroll 8
    for (int i = 0; i < 128; i += 4) {
        float4 wv = *reinterpret_cast<const float4*>(wrow + i);
        float4 qv = *reinterpret_cast<const float4*>(qrow + i);
        acc += wv.x * qv.x + wv.y * qv.y + wv.z * qv.z + wv.w * qv.w;
    }
    __shared__ float scr[256];
    scr[t] = acc;
    __syncthreads();
    if (t < 32) {
        float a = 0.f;
#pragma unroll
        for (int c2 = 0; c2 < 8; ++c2) a += scr[c2 * 32 + t];
        qs[t * CCn + dof] = a + 64.f * bias[dof];
    }
}

__global__ void k3_wq(const float* __restrict__ qs,
                      const float* __restrict__ wkc, const float* __restrict__ bkc,
                      const float* __restrict__ wkd, const float* __restrict__ bkd,
                      float* __restrict__ wq, float* __restrict__ bq) {
    int cc = blockIdx.x, wsel = blockIdx.y, b = blockIdx.z;
    const float* w = wsel ? wkd : wkc;
    int cl = threadIdx.x & 31, n = threadIdx.x >> 5;
    int c = cc * 32 + cl;
    const float* qrow = qs + b * CCn + n * DKn;
    const float* wrow = w + (size_t)(n * DKn) * CCn + c;
    float acc = 0.f;
#pragma unroll 8
    for (int d = 0; d < DKn; ++d)
        acc += qrow[d] * wrow[(size_t)d * CCn];
    wq[((size_t)b * CCn + c) * 16 + wsel * 8 + n] = acc;
    if (cc == 0 && b == 0) {
        const float* bw = wsel ? bkd : bkc;
        int pp = threadIdx.x, bb = pp >> 3, nn = pp & 7;
        float a2 = 0.f;
#pragma unroll 8
        for (int d = 0; d < DKn; ++d)
            a2 += qs[bb * CCn + nn * DKn + d] * bw[nn * DKn + d];
        bq[wsel * 256 + pp] = a2;
    }
}

__global__ void __launch_bounds__(256) k46_scorepv(
        const float* __restrict__ v, const float* __restrict__ wq,
        const float* __restrict__ bq, float* __restrict__ dsig,
        float* __restrict__ pvp, float* __restrict__ sums) {
    int sc = blockIdx.x, b = blockIdx.y;
    __shared__ u16 vt[CCn * 33];
    __shared__ float red[4][32][17];
    __shared__ float et[32 * 8];
    int t = threadIdx.x;
    int s0 = sc * 32;
    {
        int s = t & 31, c2 = t >> 5;
        const float* vb = v + ((size_t)(b * CCn + c2 * 64) << 10) + s0 + s;
#pragma unroll 8
        for (int cr = 0; cr < 64; ++cr)
            vt[(c2 * 64 + cr) * 33 + s] = f2bf(vb[(size_t)cr << 10]);
    }
    __syncthreads();
    {
        int s = t & 31, g = t >> 5;
        float ak[16];
#pragma unroll
        for (int j = 0; j < 16; ++j) ak[j] = 0.f;
        const float* wqb = wq + ((size_t)b * CCn + g * 64) * 16;
#pragma unroll 4
        for (int i = 0; i < 64; ++i) {
            float vv = bfr(vt[(g * 64 + i) * 33 + s]);
            const float* wc = wqb + i * 16;
#pragma unroll
            for (int j = 0; j < 16; ++j) ak[j] += wc[j] * vv;
        }
#pragma unroll
        for (int j = 0; j < 16; ++j) ak[j] += __shfl_xor(ak[j], 32);
        int wv = t >> 6;
        if ((t & 63) < 32) {
#pragma unroll
            for (int j = 0; j < 16; ++j) red[wv][s][j] = ak[j];
        }
    }
    __syncthreads();
    if (t < 32) {
        int s = t;
#pragma unroll
        for (int n = 0; n < NH; ++n) {
            float rc = red[0][s][n] + red[1][s][n] + red[2][s][n] + red[3][s][n];
            float rd = red[0][s][8 + n] + red[1][s][8 + n] + red[2][s][8 + n] + red[3][s][8 + n];
            float skc = (rc + bq[b * 8 + n]) * 0.125f;
            float skd = (rd + bq[256 + b * 8 + n]) * 0.125f;
            et[s * 8 + n] = __expf(skc);
            dsig[(b * NH + n) * HWn + s0 + s] = 1.f / (1.f + __expf(-skd));
        }
    }
    __syncthreads();
    if (t < 8) {
        float a = 0.f;
#pragma unroll
        for (int s = 0; s < 32; ++s) a += et[s * 8 + t];
        sums[(b * NH + t) * 32 + sc] = a;
    }
    {
        float acc0[NH], acc1[NH];
#pragma unroll
        for (int n = 0; n < NH; ++n) { acc0[n] = 0.f; acc1[n] = 0.f; }
#pragma unroll 2
        for (int s = 0; s < 32; ++s) {
            float4 ea = *reinterpret_cast<const float4*>(et + s * 8);
            float4 eb = *reinterpret_cast<const float4*>(et + s * 8 + 4);
            float va = bfr(vt[t * 33 + s]);
            float vb2 = bfr(vt[(t + 256) * 33 + s]);
            acc0[0] += ea.x * va; acc0[1] += ea.y * va; acc0[2] += ea.z * va; acc0[3] += ea.w * va;
            acc0[4] += eb.x * va; acc0[5] += eb.y * va; acc0[6] += eb.z * va; acc0[7] += eb.w * va;
            acc1[0] += ea.x * vb2; acc1[1] += ea.y * vb2; acc1[2] += ea.z * vb2; acc1[3] += ea.w * vb2;
            acc1[4] += eb.x * vb2; acc1[5] += eb.y * vb2; acc1[6] += eb.z * vb2; acc1[7] += eb.w * vb2;
        }
        size_t base = ((size_t)sc * BB + b) * NH;
#pragma unroll
        for (int n = 0; n < NH; ++n) {
            pvp[(base + n) * CCn + t] = acc0[n];
            pvp[(base + n) * CCn + t + 256] = acc1[n];
        }
    }
}

__global__ void k7_attn(const float* __restrict__ pvp, const float* __restrict__ sums,
                        const float* __restrict__ wvs, const float* __restrict__ bvs,
                        float* __restrict__ attn) {
    int n = blockIdx.x, b = blockIdx.y;
    __shared__ float pvl[CCn];
    __shared__ float scr[64 * 5];
    __shared__ float sinv;
    int t = threadIdx.x;
    if (t == 0) {
        float a = 0.f;
#pragma unroll
        for (int sc = 0; sc < 32; ++sc) a += sums[(b * NH + n) * 32 + sc];
        sinv = 1.f / a;
    }
    for (int c = t; c < CCn; c += 256) {
        float acc = 0.f;
#pragma unroll 4
        for (int sc = 0; sc < 32; ++sc)
            acc += pvp[(((size_t)sc * BB + b) * NH + n) * CCn + c];
        pvl[c] = acc;
    }
    __syncthreads();
    int d = t & 63, qq = t >> 6;
    const float* wrow = wvs + (size_t)(n * DKn + d) * CCn + qq * 128;
    const float* pq = pvl + qq * 128;
    float acc = 0.f;
#pragma unroll 4
    for (int i = 0; i < 128; ++i) acc += pq[i] * wrow[i];
    scr[d * 5 + qq] = acc;
    __syncthreads();
    if (t < 64) {
        float a = (scr[t * 5] + scr[t * 5 + 1] + scr[t * 5 + 2] + scr[t * 5 + 3]) * sinv
                + bvs[n * DKn + t];
        attn[(b * NH + n) * DKn + t] = a;
    }
}

__global__ void k8_mattn(const float* __restrict__ dsig, const float* __restrict__ attn,
                         const float* __restrict__ wm, const float* __restrict__ wmb,
                         float* __restrict__ out1) {
    int b = blockIdx.x;
    __shared__ float dst[NH * 1056];
    __shared__ float al[CCn];
    __shared__ float A2[NH * 9];
    int t = threadIdx.x;
    al[t] = attn[b * CCn + t];
    al[t + 256] = attn[b * CCn + t + 256];
    for (int g = t; g < NH * HWn; g += 256) {
        int n = g >> 10, s = g & 1023;
        dst[n * 1056 + (s & 31) * 33 + (s >> 5)] = dsig[b * NH * HWn + g];
    }
    __syncthreads();
    if (t < 72) {
        int n = t / 9, tap = t % 9;
        float acc = 0.f;
#pragma unroll 8
        for (int d = 0; d < DKn; ++d)
            acc += al[n * DKn + d] * wm[(n * DKn + d) * 9 + tap];
        A2[t] = acc;
    }
    __syncthreads();
    float bm = wmb[0];
    for (int pos = t; pos < HWn; pos += 256) {
        int y = pos >> 5, x = pos & 31;
        float m = 0.f;
#pragma unroll
        for (int n = 0; n < NH; ++n) {
            const float* dn = dst + n * 1056;
#pragma unroll
            for (int dy = 0; dy < 3; ++dy) {
                int yy = y + dy - 1;
                if ((unsigned)yy < 32u) {
#pragma unroll
                    for (int dx = 0; dx < 3; ++dx) {
                        int xx = x + dx - 1;
                        if ((unsigned)xx < 32u)
                            m += A2[n * 9 + dy * 3 + dx] * dn[yy * 33 + xx];
                    }
                }
            }
        }
        out1[b * HWn + pos] = m + bm;
    }
}

__global__ void __launch_bounds__(256) k9_out(
        const float* __restrict__ v, const float* __restrict__ dsig,
        const float* __restrict__ attn,
        const float* __restrict__ gamma, const float* __restrict__ beta,
        const float* __restrict__ mean, const float* __restrict__ var,
        float* __restrict__ out0, float* __restrict__ out2) {
    int dh = blockIdx.x, n = blockIdx.y, b = blockIdx.z;
    __shared__ float dst[1056];
    __shared__ float al[16], bnA[16], bnB[16];
    int t = threadIdx.x;
#pragma unroll
    for (int k = 0; k < 4; ++k) {
        int s = t + k * 256;
        dst[(s & 31) * 33 + (s >> 5)] = dsig[(b * NH + n) * HWn + s];
    }
    if (t < 16) {
        int d = dh * 16 + t;
        al[t] = attn[(b * NH + n) * DKn + d];
        int ch = n * DKn + d;
        float A = gamma[ch] * rsqrtf(var[ch] + 1e-5f);
        bnA[t] = A;
        bnB[t] = beta[ch] - mean[ch] * A;
    }
    __syncthreads();
    int y = t >> 3, x = (t & 7) * 4;
    const float* dr = dst + y * 33 + x;
#pragma unroll 2
    for (int k = 0; k < 16; ++k) {
        int d = dh * 16 + k;
        size_t base = (((size_t)(b * CCn + n * DKn + d)) << 10) + y * 32 + x;
        float4 v4 = *reinterpret_cast<const float4*>(v + base);
        float a = al[k], A = bnA[k], Bc = bnB[k];
        float p0 = a * dr[0], p1 = a * dr[1], p2 = a * dr[2], p3 = a * dr[3];
        float4 mo = make_float4(p0, p1, p2, p3);
        *reinterpret_cast<float4*>(out2 + base) = mo;
        float o0 = p0 * A + Bc + v4.x;
        float o1 = p1 * A + Bc + v4.y;
        float o2 = p2 * A + Bc + v4.z;
        float o3 = p3 * A + Bc + v4.w;
        o0 = o0 < 0.f ? 0.1f * o0 : o0;
        o1 = o1 < 0.f ? 0.1f * o1 : o1;
        o2 = o2 < 0.f ? 0.1f * o2 : o2;
        o3 = o3 < 0.f ? 0.1f * o3 : o3;
        float4 oo = make_float4(o0, o1, o2, o3);
        *reinterpret_cast<float4*>(out0 + base) = oo;
    }
}

extern "C" void kernel_launch(void* const* d_in, const int* in_sizes, int n_in,
                              void* d_out, int out_size, void* d_ws, size_t ws_size,
                              hipStream_t stream) {
    (void)in_sizes; (void)n_in; (void)out_size; (void)ws_size;
    const float* q   = (const float*)d_in[0];
    const float* v   = (const float*)d_in[1];
    const float* wqs = (const float*)d_in[3];
    const float* bqs = (const float*)d_in[4];
    const float* wkc = (const float*)d_in[7];
    const float* bkc = (const float*)d_in[8];
    const float* wkd = (const float*)d_in[9];
    const float* bkd = (const float*)d_in[10];
    const float* wvs = (const float*)d_in[11];
    const float* bvs = (const float*)d_in[12];
    const float* wm  = (const float*)d_in[13];
    const float* wmb = (const float*)d_in[14];
    const float* gam = (const float*)d_in[15];
    const float* bet = (const float*)d_in[16];
    const float* mea = (const float*)d_in[17];
    const float* var = (const float*)d_in[18];

    float* ws = (float*)d_ws;
    float* out0 = (float*)d_out;        // (32,512,32,32)
    float* out1 = out0 + 16777216;      // (32,1024)
    float* out2 = out1 + 32768;         // (32,512,32,32)

    static int mode = -1;
    if (mode < 0) {
        hipError_t e = hipFuncSetAttribute(reinterpret_cast<const void*>(mega),
                                           hipFuncAttributeMaxDynamicSharedMemorySize,
                                           POOLB);
        mode = (e == hipSuccess) ? 1 : 0;
    }

    if (mode == 1) {
        MArgs a;
        a.q = q; a.v = v; a.wqs = wqs; a.bqs = bqs; a.wkc = wkc; a.bkc = bkc;
        a.wkd = wkd; a.bkd = bkd; a.wvs = wvs; a.bvs = bvs; a.wm = wm; a.wmb = wmb;
        a.gam = gam; a.bet = bet; a.mea = mea; a.var = var;
        a.qsp  = ws;            //   32768
        a.qs   = ws + 32768;    //   16384
        a.wq   = ws + 49152;    //  262144
        a.bq   = ws + 311296;   //    1024 (stride 32/b, 128B-padded)
        a.dsig = ws + 312320;   //  262144
        a.sums = ws + 574464;   //    4096 (512B/b, aligned)
        a.attn = ws + 578560;   //   16384
        a.A2g  = ws + 594944;   //    3072 (stride 96/b, 384B)
        a.pvp  = ws + 598016;   // 2097152 (16 chunks)
        a.bar  = (u32*)(ws + 2695168);  // 512*16 slot words
        a.out0 = out0; a.out1 = out1; a.out2 = out2;
        kinit<<<dim3(8), dim3(256), 0, stream>>>(a.bar);
        mega<<<dim3(NBLK), dim3(256), POOLB, stream>>>(a);
        return;
    }

    // ---- fallback: proven 7-kernel pipeline ----
    float* qsp  = ws + 0;
    float* qs   = ws + 32768;
    float* wq   = ws + 49152;
    float* bq   = ws + 311296;
    float* dsig = ws + 311808;
    float* sums = ws + 573952;
    float* attn = ws + 582144;
    float* pvp  = ws + 598528;

    k1_qsum_pre<<<dim3(4, 32), 256, 0, stream>>>(q, qsp);
    k2_qsum<<<dim3(512), 256, 0, stream>>>(qsp, wqs, bqs, qs);
    k3_wq<<<dim3(16, 2, 32), 256, 0, stream>>>(qs, wkc, bkc, wkd, bkd, wq, bq);
    k46_scorepv<<<dim3(32, 32), 256, 0, stream>>>(v, wq, bq, dsig, pvp, sums);
    k7_attn<<<dim3(8, 32), 256, 0, stream>>>(pvp, sums, wvs, bvs, attn);
    k8_mattn<<<dim3(32), 256, 0, stream>>>(dsig, attn, wm, wmb, out1);
    k9_out<<<dim3(4, 8, 32), 256, 0, stream>>>(v, dsig, attn, gam, bet, mea, var, out0, out2);
}